// Round 16
// baseline (24.890 us; speedup 1.0000x reference)
//
#include <hip/hip_runtime.h>
#include <math.h>

// Chamfer distance, B=8, N=M=4096, D=3, fp32.
// R14 = R13 with DUP=1 (diagnostic removed). R13's DUPx3 measured the
// register-pressure-fixed fused kernel at F ~= 12.1us/1x (vs R12's ~17.5):
// one MFMA + one acc[16] live at a time, two sequential passes, unroll 2.
// K-packing (verified absmax=0 since R7):
//   slots 0-2 hiA*hiB | 3-5 hiA*loB | 6-8 loA*hiB | 9-11 loA*loB
//   slot 12,13 sqA_hi,lo * 1 | slot 14,15 1 * sqB_hi,lo
//   => D[r][c] = sqA_r + sqB_c - 2 a_r.b_c  (fp32 accum)
// Floors: MFMA 3.4us, VALU-min 3.4us (overlap) .. ~7us (issue-serialized).

typedef __attribute__((ext_vector_type(8)))  short bf16x8;
typedef __attribute__((ext_vector_type(16))) float f32x16;
typedef float f32x2 __attribute__((ext_vector_type(2)));

#define NPTS 4096
#define BATCH 8
#define NBLK_WORK 1024

union FragCast { uint4 u; bf16x8 v; };

__device__ __forceinline__ unsigned short f2bf(float f) {
    unsigned u = __float_as_uint(f);
    return (unsigned short)((u + 0x7FFFu + ((u >> 16) & 1u)) >> 16);
}
__device__ __forceinline__ float bf2f(unsigned short h) {
    return __uint_as_float(((unsigned)h) << 16);
}
__device__ __forceinline__ unsigned pk(unsigned short a, unsigned short b) {
    return (unsigned)a | ((unsigned)b << 16);
}

__device__ __forceinline__ void build_afrag(float x, float y, float z,
                                            uint4& a0, uint4& a1) {
    float sq  = fmaf(x, x, fmaf(y, y, z * z));
    float m2x = -2.0f * x, m2y = -2.0f * y, m2z = -2.0f * z;
    unsigned short hx = f2bf(m2x), hy = f2bf(m2y), hz = f2bf(m2z);
    unsigned short lx = f2bf(m2x - bf2f(hx));
    unsigned short ly = f2bf(m2y - bf2f(hy));
    unsigned short lz = f2bf(m2z - bf2f(hz));
    unsigned short sh = f2bf(sq);
    unsigned short sl = f2bf(sq - bf2f(sh));
    const unsigned short ONE = 0x3F80;
    a0 = make_uint4(pk(hx, hy), pk(hz, hx), pk(hy, hz), pk(lx, ly));
    a1 = make_uint4(pk(lz, lx), pk(ly, lz), pk(sh, sl), pk(ONE, ONE));
}

__device__ __forceinline__ uint4 build_bfrag(float x, float y, float z, int hf) {
    float sq = fmaf(x, x, fmaf(y, y, z * z));
    unsigned short px = f2bf(x), py = f2bf(y), pz = f2bf(z);
    unsigned short qx = f2bf(x - bf2f(px));
    unsigned short qy = f2bf(y - bf2f(py));
    unsigned short qz = f2bf(z - bf2f(pz));
    unsigned short sh = f2bf(sq);
    unsigned short sl = f2bf(sq - bf2f(sh));
    const unsigned short ONE = 0x3F80;
    return hf == 0
        ? make_uint4(pk(px, py), pk(pz, qx), pk(qy, qz), pk(px, py))
        : make_uint4(pk(pz, qx), pk(qy, qz), pk(ONE, ONE), pk(sh, sl));
}

// ---------------- main: 1024 blocks x 256 threads (4 waves) ----------------
__global__ __launch_bounds__(256, 4) void chamfer_fused(
    const float* __restrict__ pcs1, const float* __restrict__ pcs2,
    float* __restrict__ cpart, unsigned* __restrict__ counter)
{
    __shared__ uint4 afrag[2048];   // 32 tiles * 2 K-halves * 32 rows = 32 KB

    const int bid = blockIdx.x;
    const int dir = bid >> 9;
    const int b   = (bid >> 6) & 7;
    const int rq  = (bid >> 4) & 3;
    const int mg  = bid & 15;
    const int tid = threadIdx.x;

    if (bid == 0 && tid == 0) *counter = 0u;    // reset for red1 (each call)

    const float* bbase = (dir ? pcs2 : pcs1) + (size_t)b * NPTS * 3;
    const float* abase = (dir ? pcs1 : pcs2) + (size_t)b * NPTS * 3;

    const int w   = tid >> 6;
    const int l   = tid & 63;
    const int hf  = l >> 5;
    const int ln  = l & 31;

    // ---- stage A-frags: quarter rq (1024 points), built on the fly ----
    {
        const float4* src = (const float4*)(abase + (size_t)rq * 3072);
        float4 f0 = src[3 * tid + 0];
        float4 f1 = src[3 * tid + 1];
        float4 f2 = src[3 * tid + 2];
        float xs[4] = {f0.x, f0.w, f1.z, f2.y};
        float ys[4] = {f0.y, f1.x, f1.w, f2.z};
        float zs[4] = {f0.z, f1.y, f2.x, f2.w};
        const int jt = tid >> 3;
        const int r0 = (tid & 7) * 4;
#pragma unroll
        for (int i = 0; i < 4; ++i) {
            uint4 a0, a1;
            build_afrag(xs[i], ys[i], zs[i], a0, a1);
            afrag[jt * 64 + r0 + i]      = a0;
            afrag[jt * 64 + 32 + r0 + i] = a1;
        }
    }
    __syncthreads();

    const f32x16 cz = {0.f,0.f,0.f,0.f,0.f,0.f,0.f,0.f,
                       0.f,0.f,0.f,0.f,0.f,0.f,0.f,0.f};

    // ---- two sequential passes: one m-tile, one acc[16], one D live ----
#pragma unroll 1
    for (int p = 0; p < 2; ++p) {
        const int mt = mg * 8 + w * 2 + p;

        FragCast bq;
        {
            const float* s = bbase + (size_t)(mt * 32 + ln) * 3;
            bq.u = build_bfrag(s[0], s[1], s[2], hf);
        }

        float acc[16];
#pragma unroll
        for (int i = 0; i < 16; ++i) acc[i] = 3.4e38f;

#pragma unroll 2
        for (int j = 0; j < 32; ++j) {
            FragCast aq;
            aq.u = afrag[j * 64 + hf * 32 + ln];
            f32x16 D = __builtin_amdgcn_mfma_f32_32x32x16_bf16(
                aq.v, bq.v, cz, 0, 0, 0);
#pragma unroll
            for (int i = 0; i < 16; ++i) acc[i] = fminf(acc[i], D[i]);
        }

        // epilogue: 15-op tree once, cross-half, store
        float m0 = fminf(acc[0],  acc[1]);
        float m1 = fminf(acc[2],  acc[3]);
        float m2 = fminf(acc[4],  acc[5]);
        float m3 = fminf(acc[6],  acc[7]);
        float m4 = fminf(acc[8],  acc[9]);
        float m5 = fminf(acc[10], acc[11]);
        float m6 = fminf(acc[12], acc[13]);
        float m7 = fminf(acc[14], acc[15]);
        float r  = fminf(fminf(fminf(m0, m1), fminf(m2, m3)),
                         fminf(fminf(m4, m5), fminf(m6, m7)));
        r = fminf(r, __shfl_xor(r, 32, 64));

        if (l < 32) {
            cpart[((((size_t)(dir * 8 + b) * 128 + mt) * 4 + rq) << 5) + ln] =
                fmaxf(r, 0.0f);                 // clamp cancellation
        }
    }
}

// ---------------- red1: 65536 col-mins -> scalar (last-block-done) --------
__global__ __launch_bounds__(256) void chamfer_red1(
    const float* __restrict__ cpart, float* __restrict__ bpart,
    unsigned* __restrict__ counter, float* __restrict__ out)
{
    __shared__ float ws4[4];
    __shared__ int islast;
    const int t  = threadIdx.x;
    const int tg = blockIdx.x * 256 + t;        // [0, 65536): (dir,b,mt,ln)
    const float* p = cpart + ((size_t)(tg >> 5) << 7) + (tg & 31);
    float m = fminf(fminf(p[0], p[32]), fminf(p[64], p[96]));  // min over rq
    float s = sqrtf(m);                          // clamped in main
#pragma unroll
    for (int off = 1; off < 64; off <<= 1) s += __shfl_xor(s, off, 64);
    if ((t & 63) == 0) ws4[t >> 6] = s;
    __syncthreads();
    if (t == 0) {
        bpart[blockIdx.x] = ws4[0] + ws4[1] + ws4[2] + ws4[3];
        __threadfence();
        islast = (atomicAdd(counter, 1u) == 255u);
    }
    __syncthreads();
    if (islast) {                                // whole block participates
        __threadfence();
        float v = bpart[t];
#pragma unroll
        for (int off = 1; off < 64; off <<= 1) v += __shfl_xor(v, off, 64);
        if ((t & 63) == 0) ws4[t >> 6] = v;
        __syncthreads();
        if (t == 0)
            out[0] = (ws4[0] + ws4[1] + ws4[2] + ws4[3]) * (1.0f / 65536.0f);
        // loss = 0.5*(sum1/32768 + sum2/32768) = (sum1+sum2)/65536
    }
}

// ---------------- fallback (proven R5 vector path, 4KB ws) ----------------
#define CPAIRS 1024
#define PA 16
#define RSTRIDE 68

__device__ __forceinline__ f32x2 pk_fma_lo(f32x2 c, f32x2 q, f32x2 acc) {
    f32x2 d;
    asm("v_pk_fma_f32 %0, %1, %2, %3 op_sel:[0,0,0] op_sel_hi:[0,1,1]"
        : "=v"(d) : "v"(c), "v"(q), "v"(acc));
    return d;
}
__device__ __forceinline__ f32x2 pk_fma_hi(f32x2 c, f32x2 q, f32x2 acc) {
    f32x2 d;
    asm("v_pk_fma_f32 %0, %1, %2, %3 op_sel:[1,0,0] op_sel_hi:[1,1,1]"
        : "=v"(d) : "v"(c), "v"(q), "v"(acc));
    return d;
}
__device__ __forceinline__ void vmin3(float& acc, float a, float b) {
    asm("v_min3_f32 %0, %1, %2, %3" : "=v"(acc) : "v"(acc), "v"(a), "v"(b));
}

__global__ __launch_bounds__(256, 4) void chamfer_vec(
    const float* __restrict__ pcs1, const float* __restrict__ pcs2,
    float* __restrict__ partials)
{
    __shared__ float4 lds[2 * CPAIRS];
    float4* bx = lds;
    float4* bz = lds + CPAIRS;

    const int bid = blockIdx.x;
    const int dir = bid >> 9;
    const int b   = (bid >> 6) & 7;
    const int ach = bid & 63;

    const float* A  = dir ? pcs2 : pcs1;
    const float* Bp = dir ? pcs1 : pcs2;
    const float* abase = A  + (size_t)b * NPTS * 3;
    const float* bbase = Bp + (size_t)b * NPTS * 3;

    const int tid = threadIdx.x;
    const int w   = tid >> 6;
    const int l   = tid & 63;

    const int apt = ach * 64 + w * PA;
    f32x2 cx[PA / 2], cy[PA / 2], cz2[PA / 2];
    float tmin[PA];
#pragma unroll
    for (int p2 = 0; p2 < PA / 2; ++p2) {
        const float* s = abase + (size_t)(apt + 2 * p2) * 3;
        cx[p2]  = (f32x2){-2.0f * s[0], -2.0f * s[3]};
        cy[p2]  = (f32x2){-2.0f * s[1], -2.0f * s[4]};
        cz2[p2] = (f32x2){-2.0f * s[2], -2.0f * s[5]};
        tmin[2 * p2] = 3.4e38f; tmin[2 * p2 + 1] = 3.4e38f;
    }

    for (int c = 0; c < 2; ++c) {
        if (c) __syncthreads();
#pragma unroll
        for (int i = 0; i < CPAIRS / 256; ++i) {
            int j  = i * 256 + tid;
            const float* s = bbase + (size_t)(c * CPAIRS + j) * 6;
            float x0 = s[0], y0 = s[1], z0 = s[2];
            float x1 = s[3], y1 = s[4], z1 = s[5];
            bx[j] = make_float4(x0, x1, y0, y1);
            bz[j] = make_float4(z0, z1,
                                fmaf(x0, x0, fmaf(y0, y0, z0 * z0)),
                                fmaf(x1, x1, fmaf(y1, y1, z1 * z1)));
        }
        __syncthreads();
#pragma unroll 4
        for (int t = 0; t < CPAIRS / 64; ++t) {
            float4 X = bx[t * 64 + l];
            float4 Z = bz[t * 64 + l];
            f32x2 qx = (f32x2){X.x, X.y};
            f32x2 qy = (f32x2){X.z, X.w};
            f32x2 qz = (f32x2){Z.x, Z.y};
            f32x2 qw = (f32x2){Z.z, Z.w};
#pragma unroll
            for (int p2 = 0; p2 < PA / 2; ++p2) {
                f32x2 d0 = pk_fma_lo(cz2[p2], qz, qw);
                d0 = pk_fma_lo(cy[p2], qy, d0);
                d0 = pk_fma_lo(cx[p2], qx, d0);
                vmin3(tmin[2 * p2], d0.x, d0.y);
                f32x2 d1 = pk_fma_hi(cz2[p2], qz, qw);
                d1 = pk_fma_hi(cy[p2], qy, d1);
                d1 = pk_fma_hi(cx[p2], qx, d1);
                vmin3(tmin[2 * p2 + 1], d1.x, d1.y);
            }
        }
    }

    __syncthreads();
    float* lds2 = (float*)lds;
#pragma unroll
    for (int p = 0; p < PA; ++p)
        lds2[(w * PA + p) * RSTRIDE + l] = tmin[p];
    __syncthreads();

    if (tid < 64) {
        const int g = tid;
        float m = 3.4e38f;
        const float4* row = (const float4*)&lds2[g * RSTRIDE];
#pragma unroll
        for (int i = 0; i < 16; ++i) {
            float4 v = row[i];
            m = fminf(fminf(m, fminf(v.x, v.y)), fminf(v.z, v.w));
        }
        const int ap = ach * 64 + g;
        float x = abase[ap * 3 + 0], y = abase[ap * 3 + 1], z = abase[ap * 3 + 2];
        float s = sqrtf(fmaxf(fmaf(x, x, fmaf(y, y, z * z)) + m, 0.0f));
#pragma unroll
        for (int off = 1; off < 64; off <<= 1) s += __shfl_xor(s, off, 64);
        if (g == 0) partials[bid] = s;
    }
}

__global__ __launch_bounds__(256) void chamfer_final(
    const float* __restrict__ partials, int n, float scale,
    float* __restrict__ out)
{
    __shared__ float ws4[4];
    const int t = threadIdx.x;
    float v = 0.0f;
    for (int i = t; i < n; i += 256) v += partials[i];
#pragma unroll
    for (int off = 1; off < 64; off <<= 1) v += __shfl_xor(v, off, 64);
    if ((t & 63) == 0) ws4[t >> 6] = v;
    __syncthreads();
    if (t == 0)
        out[0] = (ws4[0] + ws4[1] + ws4[2] + ws4[3]) * scale;
}

extern "C" void kernel_launch(void* const* d_in, const int* in_sizes, int n_in,
                              void* d_out, int out_size, void* d_ws, size_t ws_size,
                              hipStream_t stream) {
    const float* pcs1 = (const float*)d_in[0];
    const float* pcs2 = (const float*)d_in[1];
    float* out = (float*)d_out;

    const size_t MB = 1048576;
    const size_t need = MB + 4096;

    if (ws_size >= need) {
        char* w = (char*)d_ws;
        float*    cpart   = (float*)(w);
        float*    bpart   = (float*)(w + MB);
        unsigned* counter = (unsigned*)(w + MB + 1024);

        chamfer_fused<<<dim3(NBLK_WORK), dim3(256), 0, stream>>>(
            pcs1, pcs2, cpart, counter);
        chamfer_red1 <<<dim3(256), dim3(256), 0, stream>>>(
            cpart, bpart, counter, out);
    } else {
        float* partials = (float*)d_ws;
        chamfer_vec  <<<dim3(1024), dim3(256), 0, stream>>>(pcs1, pcs2, partials);
        chamfer_final<<<dim3(1),    dim3(256), 0, stream>>>(
            partials, 1024, 1.0f / 65536.0f, out);
    }
}

// Round 17
// 24.565 us; speedup vs baseline: 1.0133x; 1.0133x over previous
//
#include <hip/hip_runtime.h>
#include <math.h>

// Chamfer distance, B=8, N=M=4096, D=3, fp32.
// R14 = R13 with DUP=1 (diagnostic removed). R13's DUPx3 measured the
// register-pressure-fixed fused kernel at F ~= 12.1us/1x (vs R12's ~17.5):
// one MFMA + one acc[16] live at a time, two sequential passes, unroll 2.
// K-packing (verified absmax=0 since R7):
//   slots 0-2 hiA*hiB | 3-5 hiA*loB | 6-8 loA*hiB | 9-11 loA*loB
//   slot 12,13 sqA_hi,lo * 1 | slot 14,15 1 * sqB_hi,lo
//   => D[r][c] = sqA_r + sqB_c - 2 a_r.b_c  (fp32 accum)
// Floors: MFMA 3.4us, VALU-min 3.4us (overlap) .. ~7us (issue-serialized).

typedef __attribute__((ext_vector_type(8)))  short bf16x8;
typedef __attribute__((ext_vector_type(16))) float f32x16;
typedef float f32x2 __attribute__((ext_vector_type(2)));

#define NPTS 4096
#define BATCH 8
#define NBLK_WORK 1024

union FragCast { uint4 u; bf16x8 v; };

__device__ __forceinline__ unsigned short f2bf(float f) {
    unsigned u = __float_as_uint(f);
    return (unsigned short)((u + 0x7FFFu + ((u >> 16) & 1u)) >> 16);
}
__device__ __forceinline__ float bf2f(unsigned short h) {
    return __uint_as_float(((unsigned)h) << 16);
}
__device__ __forceinline__ unsigned pk(unsigned short a, unsigned short b) {
    return (unsigned)a | ((unsigned)b << 16);
}

__device__ __forceinline__ void build_afrag(float x, float y, float z,
                                            uint4& a0, uint4& a1) {
    float sq  = fmaf(x, x, fmaf(y, y, z * z));
    float m2x = -2.0f * x, m2y = -2.0f * y, m2z = -2.0f * z;
    unsigned short hx = f2bf(m2x), hy = f2bf(m2y), hz = f2bf(m2z);
    unsigned short lx = f2bf(m2x - bf2f(hx));
    unsigned short ly = f2bf(m2y - bf2f(hy));
    unsigned short lz = f2bf(m2z - bf2f(hz));
    unsigned short sh = f2bf(sq);
    unsigned short sl = f2bf(sq - bf2f(sh));
    const unsigned short ONE = 0x3F80;
    a0 = make_uint4(pk(hx, hy), pk(hz, hx), pk(hy, hz), pk(lx, ly));
    a1 = make_uint4(pk(lz, lx), pk(ly, lz), pk(sh, sl), pk(ONE, ONE));
}

__device__ __forceinline__ uint4 build_bfrag(float x, float y, float z, int hf) {
    float sq = fmaf(x, x, fmaf(y, y, z * z));
    unsigned short px = f2bf(x), py = f2bf(y), pz = f2bf(z);
    unsigned short qx = f2bf(x - bf2f(px));
    unsigned short qy = f2bf(y - bf2f(py));
    unsigned short qz = f2bf(z - bf2f(pz));
    unsigned short sh = f2bf(sq);
    unsigned short sl = f2bf(sq - bf2f(sh));
    const unsigned short ONE = 0x3F80;
    return hf == 0
        ? make_uint4(pk(px, py), pk(pz, qx), pk(qy, qz), pk(px, py))
        : make_uint4(pk(pz, qx), pk(qy, qz), pk(ONE, ONE), pk(sh, sl));
}

// ---------------- main: 1024 blocks x 256 threads (4 waves) ----------------
__global__ __launch_bounds__(256, 4) void chamfer_fused(
    const float* __restrict__ pcs1, const float* __restrict__ pcs2,
    float* __restrict__ cpart, unsigned* __restrict__ counter)
{
    __shared__ uint4 afrag[2048];   // 32 tiles * 2 K-halves * 32 rows = 32 KB

    const int bid = blockIdx.x;
    const int dir = bid >> 9;
    const int b   = (bid >> 6) & 7;
    const int rq  = (bid >> 4) & 3;
    const int mg  = bid & 15;
    const int tid = threadIdx.x;

    if (bid == 0 && tid == 0) *counter = 0u;    // reset for red1 (each call)

    const float* bbase = (dir ? pcs2 : pcs1) + (size_t)b * NPTS * 3;
    const float* abase = (dir ? pcs1 : pcs2) + (size_t)b * NPTS * 3;

    const int w   = tid >> 6;
    const int l   = tid & 63;
    const int hf  = l >> 5;
    const int ln  = l & 31;

    // ---- stage A-frags: quarter rq (1024 points), built on the fly ----
    {
        const float4* src = (const float4*)(abase + (size_t)rq * 3072);
        float4 f0 = src[3 * tid + 0];
        float4 f1 = src[3 * tid + 1];
        float4 f2 = src[3 * tid + 2];
        float xs[4] = {f0.x, f0.w, f1.z, f2.y};
        float ys[4] = {f0.y, f1.x, f1.w, f2.z};
        float zs[4] = {f0.z, f1.y, f2.x, f2.w};
        const int jt = tid >> 3;
        const int r0 = (tid & 7) * 4;
#pragma unroll
        for (int i = 0; i < 4; ++i) {
            uint4 a0, a1;
            build_afrag(xs[i], ys[i], zs[i], a0, a1);
            afrag[jt * 64 + r0 + i]      = a0;
            afrag[jt * 64 + 32 + r0 + i] = a1;
        }
    }
    __syncthreads();

    const f32x16 cz = {0.f,0.f,0.f,0.f,0.f,0.f,0.f,0.f,
                       0.f,0.f,0.f,0.f,0.f,0.f,0.f,0.f};

    // ---- two sequential passes: one m-tile, one acc[16], one D live ----
#pragma unroll 1
    for (int p = 0; p < 2; ++p) {
        const int mt = mg * 8 + w * 2 + p;

        FragCast bq;
        {
            const float* s = bbase + (size_t)(mt * 32 + ln) * 3;
            bq.u = build_bfrag(s[0], s[1], s[2], hf);
        }

        float acc[16];
#pragma unroll
        for (int i = 0; i < 16; ++i) acc[i] = 3.4e38f;

#pragma unroll 2
        for (int j = 0; j < 32; ++j) {
            FragCast aq;
            aq.u = afrag[j * 64 + hf * 32 + ln];
            f32x16 D = __builtin_amdgcn_mfma_f32_32x32x16_bf16(
                aq.v, bq.v, cz, 0, 0, 0);
#pragma unroll
            for (int i = 0; i < 16; ++i) acc[i] = fminf(acc[i], D[i]);
        }

        // epilogue: 15-op tree once, cross-half, store
        float m0 = fminf(acc[0],  acc[1]);
        float m1 = fminf(acc[2],  acc[3]);
        float m2 = fminf(acc[4],  acc[5]);
        float m3 = fminf(acc[6],  acc[7]);
        float m4 = fminf(acc[8],  acc[9]);
        float m5 = fminf(acc[10], acc[11]);
        float m6 = fminf(acc[12], acc[13]);
        float m7 = fminf(acc[14], acc[15]);
        float r  = fminf(fminf(fminf(m0, m1), fminf(m2, m3)),
                         fminf(fminf(m4, m5), fminf(m6, m7)));
        r = fminf(r, __shfl_xor(r, 32, 64));

        if (l < 32) {
            cpart[((((size_t)(dir * 8 + b) * 128 + mt) * 4 + rq) << 5) + ln] =
                fmaxf(r, 0.0f);                 // clamp cancellation
        }
    }
}

// ---------------- red1: 65536 col-mins -> scalar (last-block-done) --------
__global__ __launch_bounds__(256) void chamfer_red1(
    const float* __restrict__ cpart, float* __restrict__ bpart,
    unsigned* __restrict__ counter, float* __restrict__ out)
{
    __shared__ float ws4[4];
    __shared__ int islast;
    const int t  = threadIdx.x;
    const int tg = blockIdx.x * 256 + t;        // [0, 65536): (dir,b,mt,ln)
    const float* p = cpart + ((size_t)(tg >> 5) << 7) + (tg & 31);
    float m = fminf(fminf(p[0], p[32]), fminf(p[64], p[96]));  // min over rq
    float s = sqrtf(m);                          // clamped in main
#pragma unroll
    for (int off = 1; off < 64; off <<= 1) s += __shfl_xor(s, off, 64);
    if ((t & 63) == 0) ws4[t >> 6] = s;
    __syncthreads();
    if (t == 0) {
        bpart[blockIdx.x] = ws4[0] + ws4[1] + ws4[2] + ws4[3];
        __threadfence();
        islast = (atomicAdd(counter, 1u) == 255u);
    }
    __syncthreads();
    if (islast) {                                // whole block participates
        __threadfence();
        float v = bpart[t];
#pragma unroll
        for (int off = 1; off < 64; off <<= 1) v += __shfl_xor(v, off, 64);
        if ((t & 63) == 0) ws4[t >> 6] = v;
        __syncthreads();
        if (t == 0)
            out[0] = (ws4[0] + ws4[1] + ws4[2] + ws4[3]) * (1.0f / 65536.0f);
        // loss = 0.5*(sum1/32768 + sum2/32768) = (sum1+sum2)/65536
    }
}

// ---------------- fallback (proven R5 vector path, 4KB ws) ----------------
#define CPAIRS 1024
#define PA 16
#define RSTRIDE 68

__device__ __forceinline__ f32x2 pk_fma_lo(f32x2 c, f32x2 q, f32x2 acc) {
    f32x2 d;
    asm("v_pk_fma_f32 %0, %1, %2, %3 op_sel:[0,0,0] op_sel_hi:[0,1,1]"
        : "=v"(d) : "v"(c), "v"(q), "v"(acc));
    return d;
}
__device__ __forceinline__ f32x2 pk_fma_hi(f32x2 c, f32x2 q, f32x2 acc) {
    f32x2 d;
    asm("v_pk_fma_f32 %0, %1, %2, %3 op_sel:[1,0,0] op_sel_hi:[1,1,1]"
        : "=v"(d) : "v"(c), "v"(q), "v"(acc));
    return d;
}
__device__ __forceinline__ void vmin3(float& acc, float a, float b) {
    asm("v_min3_f32 %0, %1, %2, %3" : "=v"(acc) : "v"(acc), "v"(a), "v"(b));
}

__global__ __launch_bounds__(256, 4) void chamfer_vec(
    const float* __restrict__ pcs1, const float* __restrict__ pcs2,
    float* __restrict__ partials)
{
    __shared__ float4 lds[2 * CPAIRS];
    float4* bx = lds;
    float4* bz = lds + CPAIRS;

    const int bid = blockIdx.x;
    const int dir = bid >> 9;
    const int b   = (bid >> 6) & 7;
    const int ach = bid & 63;

    const float* A  = dir ? pcs2 : pcs1;
    const float* Bp = dir ? pcs1 : pcs2;
    const float* abase = A  + (size_t)b * NPTS * 3;
    const float* bbase = Bp + (size_t)b * NPTS * 3;

    const int tid = threadIdx.x;
    const int w   = tid >> 6;
    const int l   = tid & 63;

    const int apt = ach * 64 + w * PA;
    f32x2 cx[PA / 2], cy[PA / 2], cz2[PA / 2];
    float tmin[PA];
#pragma unroll
    for (int p2 = 0; p2 < PA / 2; ++p2) {
        const float* s = abase + (size_t)(apt + 2 * p2) * 3;
        cx[p2]  = (f32x2){-2.0f * s[0], -2.0f * s[3]};
        cy[p2]  = (f32x2){-2.0f * s[1], -2.0f * s[4]};
        cz2[p2] = (f32x2){-2.0f * s[2], -2.0f * s[5]};
        tmin[2 * p2] = 3.4e38f; tmin[2 * p2 + 1] = 3.4e38f;
    }

    for (int c = 0; c < 2; ++c) {
        if (c) __syncthreads();
#pragma unroll
        for (int i = 0; i < CPAIRS / 256; ++i) {
            int j  = i * 256 + tid;
            const float* s = bbase + (size_t)(c * CPAIRS + j) * 6;
            float x0 = s[0], y0 = s[1], z0 = s[2];
            float x1 = s[3], y1 = s[4], z1 = s[5];
            bx[j] = make_float4(x0, x1, y0, y1);
            bz[j] = make_float4(z0, z1,
                                fmaf(x0, x0, fmaf(y0, y0, z0 * z0)),
                                fmaf(x1, x1, fmaf(y1, y1, z1 * z1)));
        }
        __syncthreads();
#pragma unroll 4
        for (int t = 0; t < CPAIRS / 64; ++t) {
            float4 X = bx[t * 64 + l];
            float4 Z = bz[t * 64 + l];
            f32x2 qx = (f32x2){X.x, X.y};
            f32x2 qy = (f32x2){X.z, X.w};
            f32x2 qz = (f32x2){Z.x, Z.y};
            f32x2 qw = (f32x2){Z.z, Z.w};
#pragma unroll
            for (int p2 = 0; p2 < PA / 2; ++p2) {
                f32x2 d0 = pk_fma_lo(cz2[p2], qz, qw);
                d0 = pk_fma_lo(cy[p2], qy, d0);
                d0 = pk_fma_lo(cx[p2], qx, d0);
                vmin3(tmin[2 * p2], d0.x, d0.y);
                f32x2 d1 = pk_fma_hi(cz2[p2], qz, qw);
                d1 = pk_fma_hi(cy[p2], qy, d1);
                d1 = pk_fma_hi(cx[p2], qx, d1);
                vmin3(tmin[2 * p2 + 1], d1.x, d1.y);
            }
        }
    }

    __syncthreads();
    float* lds2 = (float*)lds;
#pragma unroll
    for (int p = 0; p < PA; ++p)
        lds2[(w * PA + p) * RSTRIDE + l] = tmin[p];
    __syncthreads();

    if (tid < 64) {
        const int g = tid;
        float m = 3.4e38f;
        const float4* row = (const float4*)&lds2[g * RSTRIDE];
#pragma unroll
        for (int i = 0; i < 16; ++i) {
            float4 v = row[i];
            m = fminf(fminf(m, fminf(v.x, v.y)), fminf(v.z, v.w));
        }
        const int ap = ach * 64 + g;
        float x = abase[ap * 3 + 0], y = abase[ap * 3 + 1], z = abase[ap * 3 + 2];
        float s = sqrtf(fmaxf(fmaf(x, x, fmaf(y, y, z * z)) + m, 0.0f));
#pragma unroll
        for (int off = 1; off < 64; off <<= 1) s += __shfl_xor(s, off, 64);
        if (g == 0) partials[bid] = s;
    }
}

__global__ __launch_bounds__(256) void chamfer_final(
    const float* __restrict__ partials, int n, float scale,
    float* __restrict__ out)
{
    __shared__ float ws4[4];
    const int t = threadIdx.x;
    float v = 0.0f;
    for (int i = t; i < n; i += 256) v += partials[i];
#pragma unroll
    for (int off = 1; off < 64; off <<= 1) v += __shfl_xor(v, off, 64);
    if ((t & 63) == 0) ws4[t >> 6] = v;
    __syncthreads();
    if (t == 0)
        out[0] = (ws4[0] + ws4[1] + ws4[2] + ws4[3]) * scale;
}

extern "C" void kernel_launch(void* const* d_in, const int* in_sizes, int n_in,
                              void* d_out, int out_size, void* d_ws, size_t ws_size,
                              hipStream_t stream) {
    const float* pcs1 = (const float*)d_in[0];
    const float* pcs2 = (const float*)d_in[1];
    float* out = (float*)d_out;

    const size_t MB = 1048576;
    const size_t need = MB + 4096;

    if (ws_size >= need) {
        char* w = (char*)d_ws;
        float*    cpart   = (float*)(w);
        float*    bpart   = (float*)(w + MB);
        unsigned* counter = (unsigned*)(w + MB + 1024);

        chamfer_fused<<<dim3(NBLK_WORK), dim3(256), 0, stream>>>(
            pcs1, pcs2, cpart, counter);
        chamfer_red1 <<<dim3(256), dim3(256), 0, stream>>>(
            cpart, bpart, counter, out);
    } else {
        float* partials = (float*)d_ws;
        chamfer_vec  <<<dim3(1024), dim3(256), 0, stream>>>(pcs1, pcs2, partials);
        chamfer_final<<<dim3(1),    dim3(256), 0, stream>>>(
            partials, 1024, 1.0f / 65536.0f, out);
    }
}

// Round 18
// 23.980 us; speedup vs baseline: 1.0380x; 1.0244x over previous
//
#include <hip/hip_runtime.h>
#include <math.h>

// Chamfer distance, B=8, N=M=4096, D=3, fp32.
// R14 = R13 with DUP=1 (diagnostic removed). R13's DUPx3 measured the
// register-pressure-fixed fused kernel at F ~= 12.1us/1x (vs R12's ~17.5):
// one MFMA + one acc[16] live at a time, two sequential passes, unroll 2.
// K-packing (verified absmax=0 since R7):
//   slots 0-2 hiA*hiB | 3-5 hiA*loB | 6-8 loA*hiB | 9-11 loA*loB
//   slot 12,13 sqA_hi,lo * 1 | slot 14,15 1 * sqB_hi,lo
//   => D[r][c] = sqA_r + sqB_c - 2 a_r.b_c  (fp32 accum)
// Floors: MFMA 3.4us, VALU-min 3.4us (overlap) .. ~7us (issue-serialized).

typedef __attribute__((ext_vector_type(8)))  short bf16x8;
typedef __attribute__((ext_vector_type(16))) float f32x16;
typedef float f32x2 __attribute__((ext_vector_type(2)));

#define NPTS 4096
#define BATCH 8
#define NBLK_WORK 1024

union FragCast { uint4 u; bf16x8 v; };

__device__ __forceinline__ unsigned short f2bf(float f) {
    unsigned u = __float_as_uint(f);
    return (unsigned short)((u + 0x7FFFu + ((u >> 16) & 1u)) >> 16);
}
__device__ __forceinline__ float bf2f(unsigned short h) {
    return __uint_as_float(((unsigned)h) << 16);
}
__device__ __forceinline__ unsigned pk(unsigned short a, unsigned short b) {
    return (unsigned)a | ((unsigned)b << 16);
}

__device__ __forceinline__ void build_afrag(float x, float y, float z,
                                            uint4& a0, uint4& a1) {
    float sq  = fmaf(x, x, fmaf(y, y, z * z));
    float m2x = -2.0f * x, m2y = -2.0f * y, m2z = -2.0f * z;
    unsigned short hx = f2bf(m2x), hy = f2bf(m2y), hz = f2bf(m2z);
    unsigned short lx = f2bf(m2x - bf2f(hx));
    unsigned short ly = f2bf(m2y - bf2f(hy));
    unsigned short lz = f2bf(m2z - bf2f(hz));
    unsigned short sh = f2bf(sq);
    unsigned short sl = f2bf(sq - bf2f(sh));
    const unsigned short ONE = 0x3F80;
    a0 = make_uint4(pk(hx, hy), pk(hz, hx), pk(hy, hz), pk(lx, ly));
    a1 = make_uint4(pk(lz, lx), pk(ly, lz), pk(sh, sl), pk(ONE, ONE));
}

__device__ __forceinline__ uint4 build_bfrag(float x, float y, float z, int hf) {
    float sq = fmaf(x, x, fmaf(y, y, z * z));
    unsigned short px = f2bf(x), py = f2bf(y), pz = f2bf(z);
    unsigned short qx = f2bf(x - bf2f(px));
    unsigned short qy = f2bf(y - bf2f(py));
    unsigned short qz = f2bf(z - bf2f(pz));
    unsigned short sh = f2bf(sq);
    unsigned short sl = f2bf(sq - bf2f(sh));
    const unsigned short ONE = 0x3F80;
    return hf == 0
        ? make_uint4(pk(px, py), pk(pz, qx), pk(qy, qz), pk(px, py))
        : make_uint4(pk(pz, qx), pk(qy, qz), pk(ONE, ONE), pk(sh, sl));
}

// ---------------- main: 1024 blocks x 256 threads (4 waves) ----------------
__global__ __launch_bounds__(256, 4) void chamfer_fused(
    const float* __restrict__ pcs1, const float* __restrict__ pcs2,
    float* __restrict__ cpart, unsigned* __restrict__ counter)
{
    __shared__ uint4 afrag[2048];   // 32 tiles * 2 K-halves * 32 rows = 32 KB

    const int bid = blockIdx.x;
    const int dir = bid >> 9;
    const int b   = (bid >> 6) & 7;
    const int rq  = (bid >> 4) & 3;
    const int mg  = bid & 15;
    const int tid = threadIdx.x;

    if (bid == 0 && tid == 0) *counter = 0u;    // reset for red1 (each call)

    const float* bbase = (dir ? pcs2 : pcs1) + (size_t)b * NPTS * 3;
    const float* abase = (dir ? pcs1 : pcs2) + (size_t)b * NPTS * 3;

    const int w   = tid >> 6;
    const int l   = tid & 63;
    const int hf  = l >> 5;
    const int ln  = l & 31;

    // ---- stage A-frags: quarter rq (1024 points), built on the fly ----
    {
        const float4* src = (const float4*)(abase + (size_t)rq * 3072);
        float4 f0 = src[3 * tid + 0];
        float4 f1 = src[3 * tid + 1];
        float4 f2 = src[3 * tid + 2];
        float xs[4] = {f0.x, f0.w, f1.z, f2.y};
        float ys[4] = {f0.y, f1.x, f1.w, f2.z};
        float zs[4] = {f0.z, f1.y, f2.x, f2.w};
        const int jt = tid >> 3;
        const int r0 = (tid & 7) * 4;
#pragma unroll
        for (int i = 0; i < 4; ++i) {
            uint4 a0, a1;
            build_afrag(xs[i], ys[i], zs[i], a0, a1);
            afrag[jt * 64 + r0 + i]      = a0;
            afrag[jt * 64 + 32 + r0 + i] = a1;
        }
    }
    __syncthreads();

    const f32x16 cz = {0.f,0.f,0.f,0.f,0.f,0.f,0.f,0.f,
                       0.f,0.f,0.f,0.f,0.f,0.f,0.f,0.f};

    // ---- two sequential passes: one m-tile, one acc[16], one D live ----
#pragma unroll 1
    for (int p = 0; p < 2; ++p) {
        const int mt = mg * 8 + w * 2 + p;

        FragCast bq;
        {
            const float* s = bbase + (size_t)(mt * 32 + ln) * 3;
            bq.u = build_bfrag(s[0], s[1], s[2], hf);
        }

        float acc[16];
#pragma unroll
        for (int i = 0; i < 16; ++i) acc[i] = 3.4e38f;

#pragma unroll 2
        for (int j = 0; j < 32; ++j) {
            FragCast aq;
            aq.u = afrag[j * 64 + hf * 32 + ln];
            f32x16 D = __builtin_amdgcn_mfma_f32_32x32x16_bf16(
                aq.v, bq.v, cz, 0, 0, 0);
#pragma unroll
            for (int i = 0; i < 16; ++i) acc[i] = fminf(acc[i], D[i]);
        }

        // epilogue: 15-op tree once, cross-half, store
        float m0 = fminf(acc[0],  acc[1]);
        float m1 = fminf(acc[2],  acc[3]);
        float m2 = fminf(acc[4],  acc[5]);
        float m3 = fminf(acc[6],  acc[7]);
        float m4 = fminf(acc[8],  acc[9]);
        float m5 = fminf(acc[10], acc[11]);
        float m6 = fminf(acc[12], acc[13]);
        float m7 = fminf(acc[14], acc[15]);
        float r  = fminf(fminf(fminf(m0, m1), fminf(m2, m3)),
                         fminf(fminf(m4, m5), fminf(m6, m7)));
        r = fminf(r, __shfl_xor(r, 32, 64));

        if (l < 32) {
            cpart[((((size_t)(dir * 8 + b) * 128 + mt) * 4 + rq) << 5) + ln] =
                fmaxf(r, 0.0f);                 // clamp cancellation
        }
    }
}

// ---------------- red1: 65536 col-mins -> scalar (last-block-done) --------
__global__ __launch_bounds__(256) void chamfer_red1(
    const float* __restrict__ cpart, float* __restrict__ bpart,
    unsigned* __restrict__ counter, float* __restrict__ out)
{
    __shared__ float ws4[4];
    __shared__ int islast;
    const int t  = threadIdx.x;
    const int tg = blockIdx.x * 256 + t;        // [0, 65536): (dir,b,mt,ln)
    const float* p = cpart + ((size_t)(tg >> 5) << 7) + (tg & 31);
    float m = fminf(fminf(p[0], p[32]), fminf(p[64], p[96]));  // min over rq
    float s = sqrtf(m);                          // clamped in main
#pragma unroll
    for (int off = 1; off < 64; off <<= 1) s += __shfl_xor(s, off, 64);
    if ((t & 63) == 0) ws4[t >> 6] = s;
    __syncthreads();
    if (t == 0) {
        bpart[blockIdx.x] = ws4[0] + ws4[1] + ws4[2] + ws4[3];
        __threadfence();
        islast = (atomicAdd(counter, 1u) == 255u);
    }
    __syncthreads();
    if (islast) {                                // whole block participates
        __threadfence();
        float v = bpart[t];
#pragma unroll
        for (int off = 1; off < 64; off <<= 1) v += __shfl_xor(v, off, 64);
        if ((t & 63) == 0) ws4[t >> 6] = v;
        __syncthreads();
        if (t == 0)
            out[0] = (ws4[0] + ws4[1] + ws4[2] + ws4[3]) * (1.0f / 65536.0f);
        // loss = 0.5*(sum1/32768 + sum2/32768) = (sum1+sum2)/65536
    }
}

// ---------------- fallback (proven R5 vector path, 4KB ws) ----------------
#define CPAIRS 1024
#define PA 16
#define RSTRIDE 68

__device__ __forceinline__ f32x2 pk_fma_lo(f32x2 c, f32x2 q, f32x2 acc) {
    f32x2 d;
    asm("v_pk_fma_f32 %0, %1, %2, %3 op_sel:[0,0,0] op_sel_hi:[0,1,1]"
        : "=v"(d) : "v"(c), "v"(q), "v"(acc));
    return d;
}
__device__ __forceinline__ f32x2 pk_fma_hi(f32x2 c, f32x2 q, f32x2 acc) {
    f32x2 d;
    asm("v_pk_fma_f32 %0, %1, %2, %3 op_sel:[1,0,0] op_sel_hi:[1,1,1]"
        : "=v"(d) : "v"(c), "v"(q), "v"(acc));
    return d;
}
__device__ __forceinline__ void vmin3(float& acc, float a, float b) {
    asm("v_min3_f32 %0, %1, %2, %3" : "=v"(acc) : "v"(acc), "v"(a), "v"(b));
}

__global__ __launch_bounds__(256, 4) void chamfer_vec(
    const float* __restrict__ pcs1, const float* __restrict__ pcs2,
    float* __restrict__ partials)
{
    __shared__ float4 lds[2 * CPAIRS];
    float4* bx = lds;
    float4* bz = lds + CPAIRS;

    const int bid = blockIdx.x;
    const int dir = bid >> 9;
    const int b   = (bid >> 6) & 7;
    const int ach = bid & 63;

    const float* A  = dir ? pcs2 : pcs1;
    const float* Bp = dir ? pcs1 : pcs2;
    const float* abase = A  + (size_t)b * NPTS * 3;
    const float* bbase = Bp + (size_t)b * NPTS * 3;

    const int tid = threadIdx.x;
    const int w   = tid >> 6;
    const int l   = tid & 63;

    const int apt = ach * 64 + w * PA;
    f32x2 cx[PA / 2], cy[PA / 2], cz2[PA / 2];
    float tmin[PA];
#pragma unroll
    for (int p2 = 0; p2 < PA / 2; ++p2) {
        const float* s = abase + (size_t)(apt + 2 * p2) * 3;
        cx[p2]  = (f32x2){-2.0f * s[0], -2.0f * s[3]};
        cy[p2]  = (f32x2){-2.0f * s[1], -2.0f * s[4]};
        cz2[p2] = (f32x2){-2.0f * s[2], -2.0f * s[5]};
        tmin[2 * p2] = 3.4e38f; tmin[2 * p2 + 1] = 3.4e38f;
    }

    for (int c = 0; c < 2; ++c) {
        if (c) __syncthreads();
#pragma unroll
        for (int i = 0; i < CPAIRS / 256; ++i) {
            int j  = i * 256 + tid;
            const float* s = bbase + (size_t)(c * CPAIRS + j) * 6;
            float x0 = s[0], y0 = s[1], z0 = s[2];
            float x1 = s[3], y1 = s[4], z1 = s[5];
            bx[j] = make_float4(x0, x1, y0, y1);
            bz[j] = make_float4(z0, z1,
                                fmaf(x0, x0, fmaf(y0, y0, z0 * z0)),
                                fmaf(x1, x1, fmaf(y1, y1, z1 * z1)));
        }
        __syncthreads();
#pragma unroll 4
        for (int t = 0; t < CPAIRS / 64; ++t) {
            float4 X = bx[t * 64 + l];
            float4 Z = bz[t * 64 + l];
            f32x2 qx = (f32x2){X.x, X.y};
            f32x2 qy = (f32x2){X.z, X.w};
            f32x2 qz = (f32x2){Z.x, Z.y};
            f32x2 qw = (f32x2){Z.z, Z.w};
#pragma unroll
            for (int p2 = 0; p2 < PA / 2; ++p2) {
                f32x2 d0 = pk_fma_lo(cz2[p2], qz, qw);
                d0 = pk_fma_lo(cy[p2], qy, d0);
                d0 = pk_fma_lo(cx[p2], qx, d0);
                vmin3(tmin[2 * p2], d0.x, d0.y);
                f32x2 d1 = pk_fma_hi(cz2[p2], qz, qw);
                d1 = pk_fma_hi(cy[p2], qy, d1);
                d1 = pk_fma_hi(cx[p2], qx, d1);
                vmin3(tmin[2 * p2 + 1], d1.x, d1.y);
            }
        }
    }

    __syncthreads();
    float* lds2 = (float*)lds;
#pragma unroll
    for (int p = 0; p < PA; ++p)
        lds2[(w * PA + p) * RSTRIDE + l] = tmin[p];
    __syncthreads();

    if (tid < 64) {
        const int g = tid;
        float m = 3.4e38f;
        const float4* row = (const float4*)&lds2[g * RSTRIDE];
#pragma unroll
        for (int i = 0; i < 16; ++i) {
            float4 v = row[i];
            m = fminf(fminf(m, fminf(v.x, v.y)), fminf(v.z, v.w));
        }
        const int ap = ach * 64 + g;
        float x = abase[ap * 3 + 0], y = abase[ap * 3 + 1], z = abase[ap * 3 + 2];
        float s = sqrtf(fmaxf(fmaf(x, x, fmaf(y, y, z * z)) + m, 0.0f));
#pragma unroll
        for (int off = 1; off < 64; off <<= 1) s += __shfl_xor(s, off, 64);
        if (g == 0) partials[bid] = s;
    }
}

__global__ __launch_bounds__(256) void chamfer_final(
    const float* __restrict__ partials, int n, float scale,
    float* __restrict__ out)
{
    __shared__ float ws4[4];
    const int t = threadIdx.x;
    float v = 0.0f;
    for (int i = t; i < n; i += 256) v += partials[i];
#pragma unroll
    for (int off = 1; off < 64; off <<= 1) v += __shfl_xor(v, off, 64);
    if ((t & 63) == 0) ws4[t >> 6] = v;
    __syncthreads();
    if (t == 0)
        out[0] = (ws4[0] + ws4[1] + ws4[2] + ws4[3]) * scale;
}

extern "C" void kernel_launch(void* const* d_in, const int* in_sizes, int n_in,
                              void* d_out, int out_size, void* d_ws, size_t ws_size,
                              hipStream_t stream) {
    const float* pcs1 = (const float*)d_in[0];
    const float* pcs2 = (const float*)d_in[1];
    float* out = (float*)d_out;

    const size_t MB = 1048576;
    const size_t need = MB + 4096;

    if (ws_size >= need) {
        char* w = (char*)d_ws;
        float*    cpart   = (float*)(w);
        float*    bpart   = (float*)(w + MB);
        unsigned* counter = (unsigned*)(w + MB + 1024);

        chamfer_fused<<<dim3(NBLK_WORK), dim3(256), 0, stream>>>(
            pcs1, pcs2, cpart, counter);
        chamfer_red1 <<<dim3(256), dim3(256), 0, stream>>>(
            cpart, bpart, counter, out);
    } else {
        float* partials = (float*)d_ws;
        chamfer_vec  <<<dim3(1024), dim3(256), 0, stream>>>(pcs1, pcs2, partials);
        chamfer_final<<<dim3(1),    dim3(256), 0, stream>>>(
            partials, 1024, 1.0f / 65536.0f, out);
    }
}